// Round 4
// baseline (76.394 us; speedup 1.0000x reference)
//
#include <hip/hip_runtime.h>

// ContrastiveLoss on MI355X — symmetric Gram, LDS-free direct-register MFMA.
// Key fact: for mfma_f32_16x16x32_bf16 on feats·featsᵀ, BOTH operand
// fragments are row-contiguous 16B chunks of feats (lane (fr,fh) wants
// feats[row + fr][kk*32 + fh*8 .. +8)), so LDS staging adds no transposition
// — direct global->VGPR loads are line-aligned and remove all barriers.
// Upper triangle only (528 tiles of 128x128, class-uniform): neg tiles
// accumulate row+col exp-sums/maxes; pos tiles dump dots, compared + reduced
// in a fused pos+finalize kernel (done-counter).

#define KGRP 8
#define FD   512
#define N1T  2048
#define NT   4096
#define TEMPW 0.02f

typedef __attribute__((ext_vector_type(8))) short short8;
typedef __attribute__((ext_vector_type(4))) float f32x4;
typedef unsigned short ushort_t;

// ---- helpers ---------------------------------------------------------------

// order-preserving float<->uint encoding for atomicMax on floats
__device__ __forceinline__ unsigned enc_ord(float f) {
  unsigned u = __float_as_uint(f);
  return (u & 0x80000000u) ? ~u : (u | 0x80000000u);
}
__device__ __forceinline__ float dec_ord(unsigned u) {
  unsigned b = (u & 0x80000000u) ? (u & 0x7fffffffu) : ~u;
  return __uint_as_float(b);
}

// f32 -> bf16 round-to-nearest-even (bit trick)
__device__ __forceinline__ ushort_t f2bf(float f) {
  unsigned u = __float_as_uint(f);
  u = (u + 0x7fffu + ((u >> 16) & 1u)) >> 16;
  return (ushort_t)u;
}

// ---- prep: bf16 convert + zero accumulators + class table + tile lists -----
__global__ __launch_bounds__(256) void prep_k(
    const float* __restrict__ f1, const float* __restrict__ f2,
    ushort_t* __restrict__ bf,
    float* __restrict__ neg_sum, unsigned* __restrict__ neg_max,
    float* __restrict__ sumS, float* __restrict__ corr,
    int* __restrict__ cnts, int* __restrict__ neg_list,
    int* __restrict__ pos_list, const int* __restrict__ ov)
{
  const int b = blockIdx.x, t = threadIdx.x;

  // f32 -> bf16 (concat feats1, feats2), 8 elems/thread
  {
    int i = b * 256 + t;
    size_t base = (size_t)i * 8;
    const size_t half = (size_t)N1T * FD;
    const float* sp = (base < half) ? (f1 + base) : (f2 + (base - half));
    float4 u0 = ((const float4*)sp)[0];
    float4 u1 = ((const float4*)sp)[1];
    short8 o;
    o[0] = (short)f2bf(u0.x); o[1] = (short)f2bf(u0.y);
    o[2] = (short)f2bf(u0.z); o[3] = (short)f2bf(u0.w);
    o[4] = (short)f2bf(u1.x); o[5] = (short)f2bf(u1.y);
    o[6] = (short)f2bf(u1.z); o[7] = (short)f2bf(u1.w);
    *(short8*)(bf + base) = o;
  }

  if (b >= 1 && b <= 16) {             // zero per-row accumulators
    int i = (b - 1) * 256 + t;
    neg_sum[i] = 0.f;
    neg_max[i] = 0u;                    // 0u < enc_ord(any float)
  }

  if (b == 0) {                         // parallel tile-list build
    __shared__ int c[16];
    if (t == 0) {
      sumS[0] = 0.f; corr[0] = 0.f;
      cnts[0] = 0; cnts[1] = 0; cnts[2] = 0;   // cnts[2] = done counter
      int excl = 0;
      for (int g = 0; g < KGRP; g++) c[g] = g;
      for (int g = 0; g < KGRP; g++) {
        if (ov[g]) c[KGRP + g] = g;
        else       { c[KGRP + g] = KGRP + excl; excl++; }
      }
    }
    __syncthreads();
    for (int p = t; p < 1024; p += 256) {
      int bi = p >> 5, bj = p & 31;
      if (bj < bi) continue;
      if (c[bi >> 1] == c[bj >> 1]) {
        int k = atomicAdd(&cnts[1], 1); pos_list[k] = (bi << 5) | bj;
      } else {
        int k = atomicAdd(&cnts[0], 1); neg_list[k] = (bi << 5) | bj;
      }
    }
  }
}

// ---- gram pass over all 528 upper-triangle tiles, no LDS -------------------
__global__ __launch_bounds__(256, 3) void gram_k(
    const ushort_t* __restrict__ bf, const int* __restrict__ cnts,
    const int* __restrict__ neg_list, const int* __restrict__ pos_list,
    float* __restrict__ neg_sum, unsigned* __restrict__ neg_max,
    float* __restrict__ pos_dots)
{
  const int nn = cnts[0];
  const int b  = blockIdx.x;
  const bool isneg = (b < nn);
  const int pr = isneg ? neg_list[b] : pos_list[b - nn];
  const int bi = pr >> 5, bj = pr & 31;
  const int brow = bi << 7, bcol = bj << 7;

  const int t    = threadIdx.x;
  const int lane = t & 63, wave = t >> 6;
  const int wrow = (wave >> 1) << 6, wcol = (wave & 1) << 6;
  const int fr   = lane & 15, fh = lane >> 4;

  // per-lane operand base pointers: row-contiguous 16B chunks
  const ushort_t* pa[4];
  const ushort_t* pb[4];
#pragma unroll
  for (int m = 0; m < 4; m++)
    pa[m] = bf + (size_t)(brow + wrow + (m << 4) + fr) * FD + (fh << 3);
#pragma unroll
  for (int n = 0; n < 4; n++)
    pb[n] = bf + (size_t)(bcol + wcol + (n << 4) + fr) * FD + (fh << 3);

  f32x4 acc[4][4];
#pragma unroll
  for (int m = 0; m < 4; m++)
#pragma unroll
    for (int n = 0; n < 4; n++)
      acc[m][n] = (f32x4){0.f, 0.f, 0.f, 0.f};

  // straight-line K loop: 128 dwordx4 loads + 256 MFMAs, no sync at all
#pragma unroll
  for (int kk = 0; kk < 16; kk++) {
    short8 a[4], bb[4];
#pragma unroll
    for (int m = 0; m < 4; m++) a[m]  = *(const short8*)(pa[m] + (kk << 5));
#pragma unroll
    for (int n = 0; n < 4; n++) bb[n] = *(const short8*)(pb[n] + (kk << 5));
#pragma unroll
    for (int m = 0; m < 4; m++)
#pragma unroll
      for (int n = 0; n < 4; n++)
        acc[m][n] = __builtin_amdgcn_mfma_f32_16x16x32_bf16(a[m], bb[n], acc[m][n], 0, 0, 0);
  }

  const int rbase = brow + wrow + (fh << 2);
  const int cbase = bcol + wcol + fr;

  if (isneg) {
    // single-exp epilogue: row sums/maxes + column sums/maxes in one sweep
    float colS[4] = {0.f, 0.f, 0.f, 0.f};
    float colM[4] = {-3.0e38f, -3.0e38f, -3.0e38f, -3.0e38f};
#pragma unroll
    for (int m = 0; m < 4; m++) {
#pragma unroll
      for (int j = 0; j < 4; j++) {
        float s = 0.f, mx = -3.0e38f;
#pragma unroll
        for (int n = 0; n < 4; n++) {
          float d = acc[m][n][j];
          float e = __expf(d * TEMPW);
          s += e; mx = fmaxf(mx, d);
          colS[n] += e; colM[n] = fmaxf(colM[n], d);
        }
#pragma unroll
        for (int o = 1; o < 16; o <<= 1) {
          s  += __shfl_xor(s, o, 64);
          mx  = fmaxf(mx, __shfl_xor(mx, o, 64));
        }
        if (fr == 0) {
          int r = rbase + (m << 4) + j;
          atomicAdd(&neg_sum[r], s);
          atomicMax(&neg_max[r], enc_ord(mx));
        }
      }
    }
#pragma unroll
    for (int n = 0; n < 4; n++) {
      float s = colS[n], mx = colM[n];
      s += __shfl_xor(s, 16, 64); mx = fmaxf(mx, __shfl_xor(mx, 16, 64));
      s += __shfl_xor(s, 32, 64); mx = fmaxf(mx, __shfl_xor(mx, 32, 64));
      if (fh == 0) {
        int c = cbase + (n << 4);
        atomicAdd(&neg_sum[c], s);
        atomicMax(&neg_max[c], enc_ord(mx));
      }
    }
  } else {
    // pos tile: dump dots to scratch (compared after neg_max is final)
    float* basep = pos_dots + (size_t)(b - nn) * 16384;
#pragma unroll
    for (int m = 0; m < 4; m++)
#pragma unroll
      for (int n = 0; n < 4; n++)
        *(f32x4*)(basep + (((m << 2) + n) << 10) + (t << 2)) = acc[m][n];
  }
}

// ---- fused pos-compare + finalize (last pos block runs the finalize) -------
__global__ __launch_bounds__(256) void pos_fin_k(
    const float* __restrict__ pos_dots, const int* __restrict__ cnts,
    const int* __restrict__ pos_list, const unsigned* __restrict__ neg_max,
    const float* __restrict__ neg_sum, const int* __restrict__ ov,
    float* __restrict__ sumS, float* __restrict__ corr,
    int* __restrict__ done, float* __restrict__ out)
{
  const int np = cnts[1];
  const int p  = blockIdx.x;
  const int t  = threadIdx.x, lane = t & 63, wave = t >> 6;

  __shared__ float wsum[4];
  __shared__ int   wcnt[4];
  __shared__ int   amLast;

  if (p < np) {
    const int pr = pos_list[p];
    const int bi = pr >> 5, bj = pr & 31;
    const int wrow = (wave >> 1) << 6, wcol = (wave & 1) << 6;
    const int fr = lane & 15, fh = lane >> 4;
    const int rbase = (bi << 7) + wrow + (fh << 2);
    const int cbase = (bj << 7) + wcol + fr;
    const float cw = ((bi < 16) == (bj < 16)) ? 1.0f : 0.5f;
    const float* basep = pos_dots + (size_t)p * 16384;

    float ssum = 0.f;
    int cc = 0;
    if (bi == bj) {
#pragma unroll
      for (int m = 0; m < 4; m++)
#pragma unroll
        for (int n = 0; n < 4; n++) {
          f32x4 v = *(const f32x4*)(basep + (((m << 2) + n) << 10) + (t << 2));
          int c = cbase + (n << 4);
#pragma unroll
          for (int j = 0; j < 4; j++) {
            int r = rbase + (m << 4) + j;
            if (r != c) {
              float d = v[j];
              ssum += d;
              cc += (d > dec_ord(neg_max[r])) ? 1 : 0;
            }
          }
        }
    } else {
      float nmr[4][4], nmc[4];
#pragma unroll
      for (int m = 0; m < 4; m++)
#pragma unroll
        for (int j = 0; j < 4; j++) nmr[m][j] = dec_ord(neg_max[rbase + (m << 4) + j]);
#pragma unroll
      for (int n = 0; n < 4; n++) nmc[n] = dec_ord(neg_max[cbase + (n << 4)]);
#pragma unroll
      for (int m = 0; m < 4; m++)
#pragma unroll
        for (int n = 0; n < 4; n++) {
          f32x4 v = *(const f32x4*)(basep + (((m << 2) + n) << 10) + (t << 2));
#pragma unroll
          for (int j = 0; j < 4; j++) {
            float d = v[j];
            ssum += d;
            cc += ((d > nmr[m][j]) ? 1 : 0) + ((d > nmc[n]) ? 1 : 0);
          }
        }
      ssum *= 2.0f;   // both orientations
    }
    ssum *= cw;

#pragma unroll
    for (int o = 1; o < 64; o <<= 1) {
      ssum += __shfl_xor(ssum, o, 64);
      cc   += __shfl_xor(cc, o, 64);
    }
    if (lane == 0) { wsum[wave] = ssum; wcnt[wave] = cc; }
    __syncthreads();
    if (t == 0) {
      float S2 = 0.f; int C2 = 0;
      for (int w = 0; w < 4; w++) { S2 += wsum[w]; C2 += wcnt[w]; }
      atomicAdd(sumS, S2);
      atomicAdd(corr, (float)C2);
    }
  }

  // completion detection (block-uniform broadcast via shared)
  if (t == 0) {
    int my = -1;
    if (p < np) { __threadfence(); my = atomicAdd(done, 1); }
    amLast = (my == np - 1) ? 1 : 0;
  }
  __syncthreads();
  if (!amLast) return;
  __threadfence();

  // finalize: loss = (sum_r W_r*log(neg_sum_r) - TEMP*sumS) / total_pos
  float aa = 0.f;
  for (int r = t; r < NT; r += 256) {
    int g = r >> 8;                     // 256-row group, 0..15
    float W = ov[g & 7] ? 383.f : 255.f;
    aa += W * __logf(neg_sum[r]);
  }
#pragma unroll
  for (int o = 1; o < 64; o <<= 1) aa += __shfl_xor(aa, o, 64);
  if (lane == 0) wsum[wave] = aa;
  __syncthreads();
  if (t == 0) {
    float sw = wsum[0] + wsum[1] + wsum[2] + wsum[3];
    float S = atomicAdd(sumS, 0.f);     // coherent read past L1
    float C = atomicAdd(corr, 0.f);
    float tp = 0.f;
    for (int g = 0; g < 16; g++) tp += 256.f * (255.f + 256.f * (ov[g & 7] ? 1.f : 0.f));
    out[0] = C / tp;
    out[1] = (sw - TEMPW * S) / tp;
  }
}

// ---- launch ----------------------------------------------------------------

extern "C" void kernel_launch(void* const* d_in, const int* in_sizes, int n_in,
                              void* d_out, int out_size, void* d_ws, size_t ws_size,
                              hipStream_t stream)
{
  const float* f1 = (const float*)d_in[0];
  const float* f2 = (const float*)d_in[1];
  const int*   ov = (const int*)d_in[2];

  char* ws = (char*)d_ws;
  ushort_t* bf       = (ushort_t*)ws;                                    // 4 MB
  float*    neg_sum  = (float*)(ws + (size_t)(4 << 20));                 // 16 KB
  unsigned* neg_max  = (unsigned*)(ws + (size_t)(4 << 20) + (16 << 10)); // 16 KB
  float*    sumS     = (float*)(ws + (size_t)(4 << 20) + (32 << 10));
  float*    corr     = sumS + 1;
  int*      cnts     = (int*)(sumS + 2);                                 // 3 ints
  int*      done     = cnts + 2;
  int*      neg_list = (int*)(ws + (size_t)(4 << 20) + (36 << 10));      // <=480
  int*      pos_list = (int*)(ws + (size_t)(4 << 20) + (40 << 10));      // <=80
  float*    pos_dots = (float*)(ws + (size_t)(4 << 20) + (64 << 10));    // 5.25 MB
  float*    out      = (float*)d_out;

  hipLaunchKernelGGL(prep_k, dim3(1024), dim3(256), 0, stream,
                     f1, f2, bf, neg_sum, neg_max, sumS, corr, cnts,
                     neg_list, pos_list, ov);
  hipLaunchKernelGGL(gram_k, dim3(528), dim3(256), 0, stream,
                     bf, cnts, neg_list, pos_list, neg_sum, neg_max, pos_dots);
  hipLaunchKernelGGL(pos_fin_k, dim3(80), dim3(256), 0, stream,
                     pos_dots, cnts, pos_list, neg_max, neg_sum, ov,
                     sumS, corr, done, out);
}

// Round 5
// 49.162 us; speedup vs baseline: 1.5539x; 1.5539x over previous
//
#include <hip/hip_runtime.h>

// ContrastiveLoss on MI355X — symmetric Gram, fused tile pass, 4-buffer
// 3-ahead counted-vmcnt LDS pipeline with bank-conflict-free XOR swizzle.
// Shapes fixed by reference setup_inputs(): K=8 groups, BS=256, F=512,
// N1=2048 rows per half, N=4096 total. 128-row tiles are class-uniform.
// Upper triangle only (528 tiles): neg tiles accumulate row+col exp-sums and
// maxes; pos tiles dump dots to scratch, compared + finalized in pos_fin_k.
//
// Swizzle (rule #21, both-sides-or-neither): global_load_lds writes linearly
// (base + lane*16), so the 16B chunk permutation is applied on the GLOBAL
// source (chunk = (t&3) ^ ((r_in>>1)&3)) and the SAME XOR on the ds_read
// side (slot = fh ^ ((fr>>1)&3)). Per 16-lane phase this spreads the 16 rows
// across all 8 bank-quads exactly 2x -> 2-way = free (m136).

#define KGRP 8
#define FD   512
#define N1T  2048
#define NT   4096
#define TEMPW 0.02f

typedef __attribute__((ext_vector_type(8))) short short8;
typedef __attribute__((ext_vector_type(4))) float f32x4;
typedef unsigned short ushort_t;

// ---- helpers ---------------------------------------------------------------

// order-preserving float<->uint encoding for atomicMax on floats
__device__ __forceinline__ unsigned enc_ord(float f) {
  unsigned u = __float_as_uint(f);
  return (u & 0x80000000u) ? ~u : (u | 0x80000000u);
}
__device__ __forceinline__ float dec_ord(unsigned u) {
  unsigned b = (u & 0x80000000u) ? (u & 0x7fffffffu) : ~u;
  return __uint_as_float(b);
}

// f32 -> bf16 round-to-nearest-even (bit trick)
__device__ __forceinline__ ushort_t f2bf(float f) {
  unsigned u = __float_as_uint(f);
  u = (u + 0x7fffu + ((u >> 16) & 1u)) >> 16;
  return (ushort_t)u;
}

// async global->LDS, 16B per lane; lds dest is wave-uniform base + lane*16
__device__ __forceinline__ void gld16(const void* g, void* l) {
  __builtin_amdgcn_global_load_lds(
      (const __attribute__((address_space(1))) unsigned*)g,
      (__attribute__((address_space(3))) unsigned*)l, 16, 0, 0);
}

// ---- prep: bf16 convert + zero accumulators + class table + tile lists -----
__global__ __launch_bounds__(256) void prep_k(
    const float* __restrict__ f1, const float* __restrict__ f2,
    ushort_t* __restrict__ bf,
    float* __restrict__ neg_sum, unsigned* __restrict__ neg_max,
    float* __restrict__ sumS, float* __restrict__ corr,
    int* __restrict__ cnts, int* __restrict__ neg_list,
    int* __restrict__ pos_list, const int* __restrict__ ov)
{
  const int b = blockIdx.x, t = threadIdx.x;

  // f32 -> bf16 (concat feats1, feats2), 8 elems/thread
  {
    int i = b * 256 + t;
    size_t base = (size_t)i * 8;
    const size_t half = (size_t)N1T * FD;
    const float* sp = (base < half) ? (f1 + base) : (f2 + (base - half));
    float4 u0 = ((const float4*)sp)[0];
    float4 u1 = ((const float4*)sp)[1];
    short8 o;
    o[0] = (short)f2bf(u0.x); o[1] = (short)f2bf(u0.y);
    o[2] = (short)f2bf(u0.z); o[3] = (short)f2bf(u0.w);
    o[4] = (short)f2bf(u1.x); o[5] = (short)f2bf(u1.y);
    o[6] = (short)f2bf(u1.z); o[7] = (short)f2bf(u1.w);
    *(short8*)(bf + base) = o;
  }

  if (b >= 1 && b <= 16) {             // zero per-row accumulators
    int i = (b - 1) * 256 + t;
    neg_sum[i] = 0.f;
    neg_max[i] = 0u;                    // 0u < enc_ord(any float)
  }

  if (b == 0) {                         // parallel tile-list build
    __shared__ int c[16];
    if (t == 0) {
      sumS[0] = 0.f; corr[0] = 0.f;
      cnts[0] = 0; cnts[1] = 0; cnts[2] = 0;   // cnts[2] = done counter
      int excl = 0;
      for (int g = 0; g < KGRP; g++) c[g] = g;
      for (int g = 0; g < KGRP; g++) {
        if (ov[g]) c[KGRP + g] = g;
        else       { c[KGRP + g] = KGRP + excl; excl++; }
      }
    }
    __syncthreads();
    for (int p = t; p < 1024; p += 256) {
      int bi = p >> 5, bj = p & 31;
      if (bj < bi) continue;
      if (c[bi >> 1] == c[bj >> 1]) {
        int k = atomicAdd(&cnts[1], 1); pos_list[k] = (bi << 5) | bj;
      } else {
        int k = atomicAdd(&cnts[0], 1); neg_list[k] = (bi << 5) | bj;
      }
    }
  }
}

// ---- gram pass over all 528 upper-triangle tiles ---------------------------
// 4-buffer LDS pipeline, stage 3 ahead, 1 barrier + counted vmcnt per step.
__global__ __launch_bounds__(256, 2) void gram_k(
    const ushort_t* __restrict__ bf, const int* __restrict__ cnts,
    const int* __restrict__ neg_list, const int* __restrict__ pos_list,
    float* __restrict__ neg_sum, unsigned* __restrict__ neg_max,
    float* __restrict__ pos_dots)
{
  __shared__ char lds[4 * 16384];      // 4 bufs x (A 8KB + B 8KB)

  const int nn = cnts[0];
  const int b  = blockIdx.x;
  const bool isneg = (b < nn);
  const int pr = isneg ? neg_list[b] : pos_list[b - nn];
  const int bi = pr >> 5, bj = pr & 31;
  const int brow = bi << 7, bcol = bj << 7;

  const int t    = threadIdx.x;
  const int lane = t & 63, wave = t >> 6;
  const int wrow = (wave >> 1) << 6, wcol = (wave & 1) << 6;
  const int fr   = lane & 15, fh = lane >> 4;

  // staging source: row r_in = t>>2, 16B chunk (t&3) XOR-swizzled by row
  const int r_in = t >> 2;
  const int csw  = (((t & 3) ^ ((t >> 3) & 3)) << 3);   // elems
  const ushort_t* gA = bf + (size_t)(brow + r_in) * FD + csw;
  const ushort_t* gB = bf + (size_t)(bcol + r_in) * FD + csw;
  const int ldsw = wave << 10;         // wave-uniform LDS byte offset

  // fragment read byte offsets (same XOR on the read side)
  const int fx = ((fh ^ ((fr >> 1) & 3)) << 4);
  int offA[4], offB[4];
#pragma unroll
  for (int m = 0; m < 4; m++) offA[m] = ((wrow + (m << 4) + fr) << 6) + fx;
#pragma unroll
  for (int n = 0; n < 4; n++) offB[n] = 8192 + ((wcol + (n << 4) + fr) << 6) + fx;

  f32x4 acc[4][4];
#pragma unroll
  for (int m = 0; m < 4; m++)
#pragma unroll
    for (int n = 0; n < 4; n++)
      acc[m][n] = (f32x4){0.f, 0.f, 0.f, 0.f};

  auto stage = [&](int s) {
    char* dst = lds + ((s & 3) * 16384) + ldsw;
    const ushort_t* a = gA + (s << 5);
    const ushort_t* p = gB + (s << 5);
    gld16(a,                   dst);
    gld16(a + (size_t)64 * FD, dst + 4096);
    gld16(p,                   dst + 8192);
    gld16(p + (size_t)64 * FD, dst + 12288);
  };

  stage(0); stage(1); stage(2);        // 12 loads in flight per wave

#pragma unroll
  for (int s = 0; s < 16; s++) {
    // wait until stage(s)'s 4 loads (oldest) have landed; keep rest in flight
    if (s < 14)       asm volatile("s_waitcnt vmcnt(8)" ::: "memory");
    else if (s == 14) asm volatile("s_waitcnt vmcnt(4)" ::: "memory");
    else              asm volatile("s_waitcnt vmcnt(0)" ::: "memory");
    __builtin_amdgcn_s_barrier();
    asm volatile("" ::: "memory");     // keep LDS reads below the barrier

    char* base = lds + (s & 3) * 16384;
    short8 a[4], bb[4];
#pragma unroll
    for (int m = 0; m < 4; m++) a[m]  = *(const short8*)(base + offA[m]);
#pragma unroll
    for (int n = 0; n < 4; n++) bb[n] = *(const short8*)(base + offB[n]);

    if (s + 3 < 16) stage(s + 3);      // refill: overwrites buf read @ s-1

#pragma unroll
    for (int m = 0; m < 4; m++)
#pragma unroll
      for (int n = 0; n < 4; n++)
        acc[m][n] = __builtin_amdgcn_mfma_f32_16x16x32_bf16(a[m], bb[n], acc[m][n], 0, 0, 0);
  }

  const int rbase = brow + wrow + (fh << 2);
  const int cbase = bcol + wcol + fr;

  if (isneg) {
    // single-exp epilogue: row sums/maxes + column sums/maxes in one sweep
    float colS[4] = {0.f, 0.f, 0.f, 0.f};
    float colM[4] = {-3.0e38f, -3.0e38f, -3.0e38f, -3.0e38f};
#pragma unroll
    for (int m = 0; m < 4; m++) {
#pragma unroll
      for (int j = 0; j < 4; j++) {
        float s = 0.f, mx = -3.0e38f;
#pragma unroll
        for (int n = 0; n < 4; n++) {
          float d = acc[m][n][j];
          float e = __expf(d * TEMPW);
          s += e; mx = fmaxf(mx, d);
          colS[n] += e; colM[n] = fmaxf(colM[n], d);
        }
#pragma unroll
        for (int o = 1; o < 16; o <<= 1) {
          s  += __shfl_xor(s, o, 64);
          mx  = fmaxf(mx, __shfl_xor(mx, o, 64));
        }
        if (fr == 0) {
          int r = rbase + (m << 4) + j;
          atomicAdd(&neg_sum[r], s);
          atomicMax(&neg_max[r], enc_ord(mx));
        }
      }
    }
#pragma unroll
    for (int n = 0; n < 4; n++) {
      float s = colS[n], mx = colM[n];
      s += __shfl_xor(s, 16, 64); mx = fmaxf(mx, __shfl_xor(mx, 16, 64));
      s += __shfl_xor(s, 32, 64); mx = fmaxf(mx, __shfl_xor(mx, 32, 64));
      if (fh == 0) {
        int c = cbase + (n << 4);
        atomicAdd(&neg_sum[c], s);
        atomicMax(&neg_max[c], enc_ord(mx));
      }
    }
  } else {
    // pos tile: dump dots to scratch (compared after neg_max is final)
    float* basep = pos_dots + (size_t)(b - nn) * 16384;
#pragma unroll
    for (int m = 0; m < 4; m++)
#pragma unroll
      for (int n = 0; n < 4; n++)
        *(f32x4*)(basep + (((m << 2) + n) << 10) + (t << 2)) = acc[m][n];
  }
}

// ---- fused pos-compare + finalize (last pos block runs the finalize) -------
__global__ __launch_bounds__(256) void pos_fin_k(
    const float* __restrict__ pos_dots, const int* __restrict__ cnts,
    const int* __restrict__ pos_list, const unsigned* __restrict__ neg_max,
    const float* __restrict__ neg_sum, const int* __restrict__ ov,
    float* __restrict__ sumS, float* __restrict__ corr,
    int* __restrict__ done, float* __restrict__ out)
{
  const int np = cnts[1];
  const int p  = blockIdx.x;
  const int t  = threadIdx.x, lane = t & 63, wave = t >> 6;

  __shared__ float wsum[4];
  __shared__ int   wcnt[4];
  __shared__ int   amLast;

  if (p < np) {
    const int pr = pos_list[p];
    const int bi = pr >> 5, bj = pr & 31;
    const int wrow = (wave >> 1) << 6, wcol = (wave & 1) << 6;
    const int fr = lane & 15, fh = lane >> 4;
    const int rbase = (bi << 7) + wrow + (fh << 2);
    const int cbase = (bj << 7) + wcol + fr;
    const float cw = ((bi < 16) == (bj < 16)) ? 1.0f : 0.5f;
    const float* basep = pos_dots + (size_t)p * 16384;

    float ssum = 0.f;
    int cc = 0;
    if (bi == bj) {
#pragma unroll
      for (int m = 0; m < 4; m++)
#pragma unroll
        for (int n = 0; n < 4; n++) {
          f32x4 v = *(const f32x4*)(basep + (((m << 2) + n) << 10) + (t << 2));
          int c = cbase + (n << 4);
#pragma unroll
          for (int j = 0; j < 4; j++) {
            int r = rbase + (m << 4) + j;
            if (r != c) {
              float d = v[j];
              ssum += d;
              cc += (d > dec_ord(neg_max[r])) ? 1 : 0;
            }
          }
        }
    } else {
      float nmr[4][4], nmc[4];
#pragma unroll
      for (int m = 0; m < 4; m++)
#pragma unroll
        for (int j = 0; j < 4; j++) nmr[m][j] = dec_ord(neg_max[rbase + (m << 4) + j]);
#pragma unroll
      for (int n = 0; n < 4; n++) nmc[n] = dec_ord(neg_max[cbase + (n << 4)]);
#pragma unroll
      for (int m = 0; m < 4; m++)
#pragma unroll
        for (int n = 0; n < 4; n++) {
          f32x4 v = *(const f32x4*)(basep + (((m << 2) + n) << 10) + (t << 2));
#pragma unroll
          for (int j = 0; j < 4; j++) {
            float d = v[j];
            ssum += d;
            cc += ((d > nmr[m][j]) ? 1 : 0) + ((d > nmc[n]) ? 1 : 0);
          }
        }
      ssum *= 2.0f;   // both orientations
    }
    ssum *= cw;

#pragma unroll
    for (int o = 1; o < 64; o <<= 1) {
      ssum += __shfl_xor(ssum, o, 64);
      cc   += __shfl_xor(cc, o, 64);
    }
    if (lane == 0) { wsum[wave] = ssum; wcnt[wave] = cc; }
    __syncthreads();
    if (t == 0) {
      float S2 = 0.f; int C2 = 0;
      for (int w = 0; w < 4; w++) { S2 += wsum[w]; C2 += wcnt[w]; }
      atomicAdd(sumS, S2);
      atomicAdd(corr, (float)C2);
    }
  }

  // completion detection (block-uniform broadcast via shared)
  if (t == 0) {
    int my = -1;
    if (p < np) { __threadfence(); my = atomicAdd(done, 1); }
    amLast = (my == np - 1) ? 1 : 0;
  }
  __syncthreads();
  if (!amLast) return;
  __threadfence();

  // finalize: loss = (sum_r W_r*log(neg_sum_r) - TEMP*sumS) / total_pos
  float aa = 0.f;
  for (int r = t; r < NT; r += 256) {
    int g = r >> 8;                     // 256-row group, 0..15
    float W = ov[g & 7] ? 383.f : 255.f;
    aa += W * __logf(neg_sum[r]);
  }
#pragma unroll
  for (int o = 1; o < 64; o <<= 1) aa += __shfl_xor(aa, o, 64);
  if (lane == 0) wsum[wave] = aa;
  __syncthreads();
  if (t == 0) {
    float sw = wsum[0] + wsum[1] + wsum[2] + wsum[3];
    float S = atomicAdd(sumS, 0.f);     // coherent read past L1
    float C = atomicAdd(corr, 0.f);
    float tp = 0.f;
    for (int g = 0; g < 16; g++) tp += 256.f * (255.f + 256.f * (ov[g & 7] ? 1.f : 0.f));
    out[0] = C / tp;
    out[1] = (sw - TEMPW * S) / tp;
  }
}

// ---- launch ----------------------------------------------------------------

extern "C" void kernel_launch(void* const* d_in, const int* in_sizes, int n_in,
                              void* d_out, int out_size, void* d_ws, size_t ws_size,
                              hipStream_t stream)
{
  const float* f1 = (const float*)d_in[0];
  const float* f2 = (const float*)d_in[1];
  const int*   ov = (const int*)d_in[2];

  char* ws = (char*)d_ws;
  ushort_t* bf       = (ushort_t*)ws;                                    // 4 MB
  float*    neg_sum  = (float*)(ws + (size_t)(4 << 20));                 // 16 KB
  unsigned* neg_max  = (unsigned*)(ws + (size_t)(4 << 20) + (16 << 10)); // 16 KB
  float*    sumS     = (float*)(ws + (size_t)(4 << 20) + (32 << 10));
  float*    corr     = sumS + 1;
  int*      cnts     = (int*)(sumS + 2);                                 // 3 ints
  int*      done     = cnts + 2;
  int*      neg_list = (int*)(ws + (size_t)(4 << 20) + (36 << 10));      // <=480
  int*      pos_list = (int*)(ws + (size_t)(4 << 20) + (40 << 10));      // <=80
  float*    pos_dots = (float*)(ws + (size_t)(4 << 20) + (64 << 10));    // 5.25 MB
  float*    out      = (float*)d_out;

  hipLaunchKernelGGL(prep_k, dim3(1024), dim3(256), 0, stream,
                     f1, f2, bf, neg_sum, neg_max, sumS, corr, cnts,
                     neg_list, pos_list, ov);
  hipLaunchKernelGGL(gram_k, dim3(528), dim3(256), 0, stream,
                     bf, cnts, neg_list, pos_list, neg_sum, neg_max, pos_dots);
  hipLaunchKernelGGL(pos_fin_k, dim3(80), dim3(256), 0, stream,
                     pos_dots, cnts, pos_list, neg_max, neg_sum, ov,
                     sumS, corr, done, out);
}